// Round 3
// baseline (5010.469 us; speedup 1.0000x reference)
//
#include <hip/hip_runtime.h>
#include <hip/hip_bf16.h>
#include <cstdint>
#include <cstddef>

// MultiScaleQuantizer: z (256,32,16,16) fp32, embed (4096,32) fp32.
// Outputs concat (fp32): f_hat (2097152), idx@pn=1..16 (87296), loss (1).
//
// r19: single fused scan replaces phaseA+phaseB, L2-direct operands replace
// LDS staging.
//  - Correctness: candidates vs running prefix-min + MARGIN. For true argmin
//    v*: d_bf16(v*) <= d(v*)+eps <= d(u)+eps <= d_bf16(u)+2eps for ALL u, so
//    any prefix-min + MARGIN (1.0 >> 2eps~0.1) strictly exceeds d_bf16(v*)
//    -> v* always collected by the block owning its chunk. Exact-fp32 rescue
//    (identical accumulation order) + atomicMin(key) -> identical winner and
//    tie-break as r16. Window 0 is pre-passed min-only to seed the threshold
//    (else window-0 collect would fire on everything).
//  - LDS conflicts were unfixable: 16B-aligned b128 reads have only 8 start
//    banks -> 8 lanes/start (measured exactly 6 extra cyc/read, 3.1M/disp).
//    Codebook is 256KB bf16 = L2-resident; B-frag, cin (se/2 replicated x4),
//    and A-frag (pre-negated bf16 z rows) are now direct 16B global loads.
//    No LDS, no barriers, no per-block af setup in the hot loop.
//  - Rescue lands in per-point LDS u64 keys, flushed once per block ->
//    global atomic count stays ~N*NVC (r17's WRITE_SIZE blowup avoided).

#define B_   256
#define V_   4096
#define NTOT 2097152   // 256*32*16*16
#define WIN  128       // codes per threshold-update window
#define CAP  2048      // candidate list capacity per block (u32 entries)

using bf16x8 = __attribute__((ext_vector_type(8))) short;
using f32x4  = __attribute__((ext_vector_type(4))) float;

__device__ inline short f2bf(float f) {
  __hip_bfloat16 h = __float2bfloat16(f);
  return *reinterpret_cast<short*>(&h);
}
__device__ inline unsigned encf(float f) {        // monotone fp32 -> u32
  unsigned u = __float_as_uint(f);
  return (u & 0x80000000u) ? ~u : (u | 0x80000000u);
}
__device__ inline int keyidx(unsigned long long k) {  // decode + clamp (safety)
  int i = (int)(unsigned)(k & 0xffffffffull);
  return min(max(i, 0), V_ - 1);
}
__device__ inline float min3f(float a, float b, float c) {
  float d;
  asm("v_min3_f32 %0, %1, %2, %3" : "=v"(d) : "v"(a), "v"(b), "v"(c));
  return d;
}

// ---- setup: f_rest=z, zrow/zrowb@pn1, ebf, sehalf4, tables, inits ----
// block = one (b,c) plane; blockIdx.x = b*32+c
__global__ __launch_bounds__(256) void setup_kernel(
    const float* __restrict__ z, const float* __restrict__ embed,
    float* __restrict__ f_rest, float* __restrict__ zrow,
    short* __restrict__ zrowb, short* __restrict__ ebf,
    float* __restrict__ sehalf4, float* __restrict__ tables,
    float* __restrict__ loss_slots, unsigned long long* __restrict__ keys0)
{
  const int tid = threadIdx.x;
  const int t = blockIdx.x * 256 + tid;
  float v = z[t];
  f_rest[t] = v;

  __shared__ float sm[256];
  sm[tid] = v;
  __syncthreads();
  if (tid == 0) {
    float s = 0.f;
    for (int i = 0; i < 256; ++i) s += sm[i];   // ref's linear i,j order
    int c = blockIdx.x & 31, b = blockIdx.x >> 5;
    float val = s * (1.0f / 256.0f);
    zrow[(size_t)b * 32 + c] = val;             // row-major [n][32]
    zrowb[(size_t)b * 32 + c] = f2bf(-val);     // negated bf16 for A-frags
  }

  if (blockIdx.x < 16) {                        // sehalf4 + ebf: 16*256 codes
    int code = blockIdx.x * 256 + tid;
    float s = 0.f;
#pragma unroll
    for (int c = 0; c < 32; ++c) {
      float e = embed[(size_t)code * 32 + c];
      ebf[(size_t)code * 32 + c] = f2bf(e);
      s += e * e;                                // sequential like ref
    }
    float h = 0.5f * s;                          // *0.5 exact
    f32x4 v4 = {h, h, h, h};
    *(f32x4*)(sehalf4 + (size_t)code * 4) = v4;  // replicated for cin loads
  } else if (blockIdx.x == 16) {
    if (tid < 64) {
      int pn_i = tid >> 4;          // 0..3 -> pn = 1,2,4,8
      int o    = tid & 15;
      int pn   = 1 << pn_i;
      double scale = (double)pn / 16.0;
      double x  = (o + 0.5) * scale - 0.5;
      double x0 = floor(x);
      double tf = x - x0;
      float row[8];
#pragma unroll
      for (int h = 0; h < 8; ++h) row[h] = 0.f;
      const double A = -0.75;
#pragma unroll
      for (int off = -1; off <= 2; ++off) {
        double s = fabs(tf - (double)off);
        double cub;
        if (s <= 1.0)      cub = ((A + 2.0) * s - (A + 3.0)) * s * s + 1.0;
        else if (s < 2.0)  cub = (((s - 5.0) * s + 8.0) * s - 4.0) * A;
        else               cub = 0.0;
        int idx = (int)x0 + off;
        idx = min(max(idx, 0), pn - 1);
        row[idx] = (float)((double)row[idx] + cub);  // numpy f32 += f64
      }
#pragma unroll
      for (int h = 0; h < 8; ++h) tables[pn_i * 128 + o * 8 + h] = row[h];
    }
  } else if (blockIdx.x == 17) {
    keys0[tid] = ~0ull;                          // pn=1: N=256
  } else if (blockIdx.x >= 20 && blockIdx.x < 60) {
    loss_slots[(blockIdx.x - 20) * 256 + tid] = 0.f;   // 40*256 = 10240 zeros
  }
}

// ------------- fused scan: min + candidates + exact rescue -----------------
// block 256 = 4 waves x 32 points (2 frags/wave); grid (N/128, NVC).
// All MFMA operands loaded L2-direct (no LDS staging, no barriers in loop).
__global__ __launch_bounds__(256) void vq_scan_kernel(
    const short* __restrict__ zrowb, const short* __restrict__ ebf,
    const float* __restrict__ sehalf4, const float* __restrict__ zrow,
    const float* __restrict__ embed, unsigned long long* __restrict__ keys,
    int vchunk)
{
  __shared__ unsigned int clist[CAP];          // (nloc<<12) | v
  __shared__ unsigned long long lkey[128];     // per-point local best key
  __shared__ int ccnt;

  const int tid = threadIdx.x;
  const int lane = tid & 63, wave = tid >> 6;
  const int col = lane & 15, quad = lane >> 4;
  const int nblk = blockIdx.x * 128;
  const int nw = nblk + wave * 32;
  const int vbase = blockIdx.y * vchunk;
  const float MARGIN = 1.0f;   // on s-scale; 2x bf16 |err| ~ 0.1 here

  if (tid < 128) lkey[tid] = ~0ull;
  if (tid == 0) ccnt = 0;
  __syncthreads();

  // A-frags: 16B loads from pre-negated bf16 z rows
  bf16x8 af[2];
#pragma unroll
  for (int f = 0; f < 2; ++f)
    af[f] = *(const bf16x8*)(zrowb + (size_t)(nw + f * 16 + col) * 32 + quad * 8);

  float mn[2][4];
#pragma unroll
  for (int f = 0; f < 2; ++f)
#pragma unroll
    for (int r = 0; r < 4; ++r) mn[f][r] = 3.4e38f;

  const short* eb = ebf + (size_t)vbase * 32;
  const float* sh = sehalf4 + (size_t)vbase * 4;

  // pre-pass: window 0 min-only (seeds the threshold)
#pragma unroll
  for (int vv = 0; vv < WIN; vv += 32) {
    bf16x8 bfA = *(const bf16x8*)(eb + (size_t)(vv + col) * 32 + quad * 8);
    bf16x8 bfB = *(const bf16x8*)(eb + (size_t)(vv + 16 + col) * 32 + quad * 8);
    f32x4 cinA = *(const f32x4*)(sh + (size_t)(vv + col) * 4);
    f32x4 cinB = *(const f32x4*)(sh + (size_t)(vv + 16 + col) * 4);
    f32x4 dA0 = __builtin_amdgcn_mfma_f32_16x16x32_bf16(af[0], bfA, cinA, 0, 0, 0);
    f32x4 dA1 = __builtin_amdgcn_mfma_f32_16x16x32_bf16(af[1], bfA, cinA, 0, 0, 0);
    f32x4 dB0 = __builtin_amdgcn_mfma_f32_16x16x32_bf16(af[0], bfB, cinB, 0, 0, 0);
    f32x4 dB1 = __builtin_amdgcn_mfma_f32_16x16x32_bf16(af[1], bfB, cinB, 0, 0, 0);
#pragma unroll
    for (int r = 0; r < 4; ++r) {
      mn[0][r] = min3f(mn[0][r], dA0[r], dB0[r]);
      mn[1][r] = min3f(mn[1][r], dA1[r], dB1[r]);
    }
  }

  // collect sweep over all windows (window 0 re-processed; L1-hot, harmless)
  for (int w0 = 0; w0 < vchunk; w0 += WIN) {
    float thr[2][4];
#pragma unroll
    for (int f = 0; f < 2; ++f)
#pragma unroll
      for (int r = 0; r < 4; ++r) thr[f][r] = mn[f][r] + MARGIN;
    float tmax = fmaxf(
        fmaxf(fmaxf(thr[0][0], thr[0][1]), fmaxf(thr[0][2], thr[0][3])),
        fmaxf(fmaxf(thr[1][0], thr[1][1]), fmaxf(thr[1][2], thr[1][3])));
    const short* ebw = eb + (size_t)w0 * 32;
    const float* shw = sh + (size_t)w0 * 4;
#pragma unroll 2
    for (int vv = 0; vv < WIN; vv += 32) {
      bf16x8 bfA = *(const bf16x8*)(ebw + (size_t)(vv + col) * 32 + quad * 8);
      bf16x8 bfB = *(const bf16x8*)(ebw + (size_t)(vv + 16 + col) * 32 + quad * 8);
      f32x4 cinA = *(const f32x4*)(shw + (size_t)(vv + col) * 4);
      f32x4 cinB = *(const f32x4*)(shw + (size_t)(vv + 16 + col) * 4);
      f32x4 dd[2][2];
      dd[0][0] = __builtin_amdgcn_mfma_f32_16x16x32_bf16(af[0], bfA, cinA, 0, 0, 0);
      dd[0][1] = __builtin_amdgcn_mfma_f32_16x16x32_bf16(af[1], bfA, cinA, 0, 0, 0);
      dd[1][0] = __builtin_amdgcn_mfma_f32_16x16x32_bf16(af[0], bfB, cinB, 0, 0, 0);
      dd[1][1] = __builtin_amdgcn_mfma_f32_16x16x32_bf16(af[1], bfB, cinB, 0, 0, 0);
      // running-min update
#pragma unroll
      for (int r = 0; r < 4; ++r) {
        mn[0][r] = min3f(mn[0][r], dd[0][0][r], dd[1][0][r]);
        mn[1][r] = min3f(mn[1][r], dd[0][1][r], dd[1][1][r]);
      }
      // coarse superset test (dd <= thr => min16 <= dd <= thr <= tmax)
      float mA0 = min3f(dd[0][0][0], dd[0][0][1], dd[0][0][2]);
      float mA1 = min3f(dd[0][0][3], dd[0][1][0], dd[0][1][1]);
      float mA2 = min3f(dd[0][1][2], dd[0][1][3], mA0);
      float mB0 = min3f(dd[1][0][0], dd[1][0][1], dd[1][0][2]);
      float mB1 = min3f(dd[1][0][3], dd[1][1][0], dd[1][1][1]);
      float mB2 = min3f(dd[1][1][2], dd[1][1][3], mB0);
      float m16 = fminf(min3f(mA1, mA2, mB1), mB2);
      if (m16 <= tmax) {   // drill down per element
#pragma unroll
        for (int s = 0; s < 2; ++s) {
#pragma unroll
          for (int f = 0; f < 2; ++f) {
#pragma unroll
            for (int r = 0; r < 4; ++r) {
              if (dd[s][f][r] <= thr[f][r]) {
                int nloc = wave * 32 + f * 16 + quad * 4 + r;
                int v = vbase + w0 + vv + s * 16 + col;
                int slot = atomicAdd(&ccnt, 1);
                if (slot < CAP) {
                  clist[slot] = ((unsigned)nloc << 12) | (unsigned)v;
                } else {
                  // overflow: exact inline (ascending-c fp order) -> lkey
                  const float* zp = zrow + (size_t)(nblk + nloc) * 32;
                  const float* ep = embed + (size_t)v * 32;
                  float dot = 0.f, sz = 0.f;
#pragma unroll 1
                  for (int i = 0; i < 32; ++i) {
                    float zc = zp[i];
                    dot = fmaf(zc, ep[i], dot);
                    sz  = fmaf(zc, zc, sz);
                  }
                  float d = fmaf(-2.0f, dot, sz) + 2.0f * sehalf4[(size_t)v * 4];
                  atomicMin(&lkey[nloc],
                            ((unsigned long long)encf(d) << 32) | (unsigned)v);
                }
              }
            }
          }
        }
      }
    }
  }

  // batch exact-fp32 rescue into LDS keys (identical fp order to passing r16)
  __syncthreads();
  int tot = min(ccnt, CAP);
  for (int j = tid; j < tot; j += 256) {
    unsigned cv = clist[j];
    int nloc = (int)(cv >> 12);
    int v = (int)(cv & 4095u);
    const float* zp = zrow + (size_t)(nblk + nloc) * 32;
    const float* ep = embed + (size_t)v * 32;
    float dot = 0.f, sz = 0.f;
#pragma unroll
    for (int i = 0; i < 32; ++i) {
      float zc = zp[i];
      dot = fmaf(zc, ep[i], dot);
      sz  = fmaf(zc, zc, sz);
    }
    float d = fmaf(-2.0f, dot, sz) + 2.0f * sehalf4[(size_t)v * 4];
    atomicMin(&lkey[nloc], ((unsigned long long)encf(d) << 32) | (unsigned)v);
  }
  __syncthreads();
  if (tid < 128) {
    unsigned long long k = lkey[tid];
    if (k != ~0ull) atomicMin(&keys[nblk + tid], k);   // 1 global atomic/pt
  }
}

// ---- upsample + f_rest update + loss + idx out + next-scale prep ----
// block = one (b,c) plane; blockIdx.x = b*32+c; tid = o*16+p
__global__ __launch_bounds__(256) void up_update_kernel(
    const float* __restrict__ embed, const unsigned long long* __restrict__ keys,
    const float* __restrict__ tbl, float* __restrict__ f_rest, int pn,
    float* __restrict__ zrow, short* __restrict__ zrowb,
    unsigned long long* __restrict__ keys_nb, int pn_next, int n_next,
    float* __restrict__ idx_out, float* __restrict__ loss_slot)
{
  __shared__ float sm[256];
  __shared__ float sm_e[64];
  const int tid = threadIdx.x;
  const int t = blockIdx.x * 256 + tid;
  const int p = tid & 15, o = tid >> 4;
  const int c = blockIdx.x & 31, b = blockIdx.x >> 5;
  const int pn2 = pn * pn;

  float pre = f_rest[t];
  sm[tid] = pre;
  if (tid < pn2) {
    int idx = keyidx(keys[b * pn2 + tid]);
    if (c == 0) idx_out[b * pn2 + tid] = (float)idx;
    sm_e[tid] = embed[(size_t)idx * 32 + c];
  }
  __syncthreads();

  // loss partial: recompute zavg from pre-update plane (== zrow exactly)
  float lsum = 0.f;
  if (tid < pn2) {
    int k = 16 / pn;
    int ph = tid / pn, pw = tid - ph * pn;
    float s = 0.f;
    for (int i = 0; i < k; ++i)
      for (int j = 0; j < k; ++j)
        s += sm[(ph * k + i) * 16 + (pw * k + j)];
    float zavg = s * (1.0f / (k * k));
    float d = sm_e[tid] - zavg;
    lsum = d * d;
  }
#pragma unroll
  for (int off = 32; off > 0; off >>= 1) lsum += __shfl_down(lsum, off, 64);
  if ((tid & 63) == 0)
    atomicAdd(loss_slot + ((blockIdx.x & 127) << 4), lsum);

  // bicubic upsample (ref: h-einsum first, then w)
  const float* Wo = tbl + o * 8;
  const float* Wp = tbl + p * 8;
  float acc = 0.f;
  for (int w = 0; w < pn; ++w) {
    float inner = 0.f;
    for (int h = 0; h < pn; ++h)
      inner = fmaf(Wo[h], sm_e[h * pn + w], inner);
    acc = fmaf(Wp[w], inner, acc);
  }
  float nr = pre - acc;
  f_rest[t] = nr;

  __syncthreads();
  sm[tid] = nr;
  __syncthreads();
  const int pnn2 = pn_next * pn_next;
  if (tid < pnn2) {
    int ph = tid / pn_next, pw = tid - ph * pn_next;
    int k = 16 / pn_next;
    float s = 0.f;
    for (int i = 0; i < k; ++i)
      for (int j = 0; j < k; ++j)
        s += sm[(ph * k + i) * 16 + (pw * k + j)];
    float zavg = s * (1.0f / (k * k));
    size_t nn = (size_t)(b * pnn2 + tid);
    zrow[nn * 32 + c]  = zavg;          // exact f32 for rescue/loss
    zrowb[nn * 32 + c] = f2bf(-zavg);   // negated bf16 A-frag source
  }
  if (t < n_next) {                // reset ping-pong keys for next scale
    keys_nb[t] = ~0ull;
  }
}

// -- final scale (pn=16): out = (z - f_rest) + embed[idx], idx out, loss --
__global__ __launch_bounds__(256) void final_add_kernel(
    const float* __restrict__ z, const float* __restrict__ f_rest,
    const float* __restrict__ embed, const unsigned long long* __restrict__ keys,
    float* __restrict__ f_hat, float* __restrict__ idx_out,
    float* __restrict__ loss_slot)
{
  const int tid = threadIdx.x;
  const int t = blockIdx.x * 256 + tid;
  const int c = blockIdx.x & 31, b = blockIdx.x >> 5;
  const int n = b * 256 + tid;
  int idx = keyidx(keys[n]);
  if (c == 0) idx_out[n] = (float)idx;
  float e = embed[(size_t)idx * 32 + c];
  float fr = f_rest[t];
  f_hat[t] = (z[t] - fr) + e;   // f_hat = sum of zq (err ~1e-6)
  float d = e - fr;             // fr == zrow value at pn=16 bit-exactly
  float lsum = d * d;
#pragma unroll
  for (int off = 32; off > 0; off >>= 1) lsum += __shfl_down(lsum, off, 64);
  if ((tid & 63) == 0)
    atomicAdd(loss_slot + ((blockIdx.x & 127) << 4), lsum);
}

// ------------- final loss reduce: 5 scales x 128 padded slots -------------
__global__ __launch_bounds__(128) void loss_final_kernel(
    const float* __restrict__ loss_slots, float* __restrict__ out_loss)
{
  __shared__ float lred[2];
  const int tid = threadIdx.x;   // 128 threads = 2 waves
  const float numel[5] = {8192.f, 32768.f, 131072.f, 524288.f, 2097152.f};
  float tot = 0.f;
  for (int s = 0; s < 5; ++s) {
    float x = loss_slots[s * 2048 + tid * 16];
#pragma unroll
    for (int off = 32; off > 0; off >>= 1) x += __shfl_down(x, off, 64);
    if ((tid & 63) == 0) lred[tid >> 6] = x;
    __syncthreads();
    if (tid == 0) {
      float m = (lred[0] + lred[1]) / numel[s];
      tot += 0.25f * m + m;        // beta*mean + mean
    }
    __syncthreads();
  }
  if (tid == 0) out_loss[0] = tot / 5.f;
}

// =========================== host launcher ===========================
extern "C" void kernel_launch(void* const* d_in, const int* in_sizes, int n_in,
                              void* d_out, int out_size, void* d_ws, size_t ws_size,
                              hipStream_t stream)
{
  const float* z     = (const float*)d_in[0];
  const float* embed = (const float*)d_in[1];
  float* out = (float*)d_out;
  float* ws  = (float*)d_ws;

  // ws layout (float slots), total 5499392 floats ~= 21.0 MiB
  float* f_rest  = ws;                                   // 2097152
  float* zrow    = ws + 2097152;                         // [65536][32] f32
  short* zrowb   = (short*)(ws + 4194304);               // [65536][32] bf16(-z)
  short* ebf     = (short*)(ws + 5242880);               // 131072 shorts
  float* sehalf4 = ws + 5308416;                         // 4096*4 replicated
  unsigned long long* keys0 = (unsigned long long*)(ws + 5324800); // 65536 u64
  unsigned long long* keys1 = (unsigned long long*)(ws + 5455872); // 16384 u64
  float* loss_slots = ws + 5488640;                      // 5*128*16 = 10240
  float* tables     = ws + 5498880;                      // 512

  unsigned long long* keysb[2] = {keys0, keys1};

  setup_kernel<<<NTOT / 256, 256, 0, stream>>>(z, embed, f_rest, zrow, zrowb,
                                               ebf, sehalf4, tables,
                                               loss_slots, keys0);

  const int PN[5]  = {1, 2, 4, 8, 16};
  const int NVC[5] = {32, 16, 8, 8, 8};   // vchunk = V_/NVC (multiple of WIN)
  int idx_off = NTOT;
  for (int i = 0; i < 5; ++i) {
    int pn = PN[i];
    int N  = B_ * pn * pn;
    int vchunk = V_ / NVC[i];
    unsigned long long* kb = keysb[i & 1];
    dim3 g(N / 128, NVC[i]);
    vq_scan_kernel<<<g, 256, 0, stream>>>(zrowb, ebf, sehalf4, zrow, embed,
                                          kb, vchunk);
    if (i < 4) {
      int pnn = PN[i + 1];
      up_update_kernel<<<NTOT / 256, 256, 0, stream>>>(
          embed, kb, tables + i * 128, f_rest, pn,
          zrow, zrowb, keysb[(i + 1) & 1],
          pnn, B_ * pnn * pnn, out + idx_off, loss_slots + i * 2048);
    } else {
      final_add_kernel<<<NTOT / 256, 256, 0, stream>>>(
          z, f_rest, embed, kb, out, out + idx_off, loss_slots + 4 * 2048);
    }
    idx_off += N;
  }
  loss_final_kernel<<<1, 128, 0, stream>>>(loss_slots, out + 2184448);
}

// Round 4
// 496.222 us; speedup vs baseline: 10.0972x; 10.0972x over previous
//
#include <hip/hip_runtime.h>
#include <hip/hip_bf16.h>
#include <cstdint>
#include <cstddef>

// MultiScaleQuantizer: z (256,32,16,16) fp32, embed (4096,32) fp32.
// Outputs concat (fp32): f_hat (2097152), idx@pn=1..16 (87296), loss (1).
//
// r20: single fused scan kernel (phaseA deleted) with near-global threshold
// quality -- the r19 lesson was that per-chunk prefix-min over small chunks
// explodes candidates (11.9M LDS-conflict cycles of lkey/ccnt serialization).
//  - Bigger chunks (pn16: 1024 codes), window 0 scanned MIN-ONLY first,
//    collect passes use running prefix-min (butterflied across cols each
//    window, + MARGIN), window 0 collected LAST with full-chunk min.
//    Correct: for exact argmin v*, d_bf16(v*) <= min_bf16(anySubset) + 2eps
//    (2eps ~ 0.1 << MARGIN=1.0), so v* is always collected; exact-fp32
//    rescue (identical fp order) + atomicMin key -> identical winner.
//  - Keeps r16's proven LDS staging for B-frags (padded 80B rows) + scalar
//    selds (r18's cin-from-LDS regressed: LDS pipe is the tight resource).
//  - Adopts r19's verified-correct zrow/zrowb: af = one coalesced 16B load
//    of pre-negated bf16 rows (replaces 16 strided f32 loads + f2bf /frag).
//  - Rescue pre-reduces into per-point LDS u64 keys; 128 global atomics per
//    block regardless of candidate count.

#define B_   256
#define V_   4096
#define NTOT 2097152   // 256*32*16*16
#define WIN  128       // codebook window staged in LDS
#define CAP  2048      // candidate list capacity per block (u32 entries)
#define MARGIN_ 1.0f

using bf16x8 = __attribute__((ext_vector_type(8))) short;
using f32x4  = __attribute__((ext_vector_type(4))) float;

__device__ inline short f2bf(float f) {
  __hip_bfloat16 h = __float2bfloat16(f);
  return *reinterpret_cast<short*>(&h);
}
__device__ inline unsigned encf(float f) {        // monotone fp32 -> u32
  unsigned u = __float_as_uint(f);
  return (u & 0x80000000u) ? ~u : (u | 0x80000000u);
}
__device__ inline int keyidx(unsigned long long k) {  // decode + clamp (safety)
  int i = (int)(unsigned)(k & 0xffffffffull);
  return min(max(i, 0), V_ - 1);
}
__device__ inline float min3f(float a, float b, float c) {
  float d;
  asm("v_min3_f32 %0, %1, %2, %3" : "=v"(d) : "v"(a), "v"(b), "v"(c));
  return d;
}

// ---- setup: f_rest=z, zrow/zrowb@pn1, ebf, se, tables, inits ----
// block = one (b,c) plane; blockIdx.x = b*32+c
__global__ __launch_bounds__(256) void setup_kernel(
    const float* __restrict__ z, const float* __restrict__ embed,
    float* __restrict__ f_rest, float* __restrict__ zrow,
    short* __restrict__ zrowb, short* __restrict__ ebf,
    float* __restrict__ se, float* __restrict__ tables,
    float* __restrict__ loss_slots, unsigned long long* __restrict__ keys0)
{
  const int tid = threadIdx.x;
  const int t = blockIdx.x * 256 + tid;
  float v = z[t];
  f_rest[t] = v;

  __shared__ float sm[256];
  sm[tid] = v;
  __syncthreads();
  if (tid == 0) {
    float s = 0.f;
    for (int i = 0; i < 256; ++i) s += sm[i];   // ref's linear i,j order
    int c = blockIdx.x & 31, b = blockIdx.x >> 5;
    float val = s * (1.0f / 256.0f);
    zrow[(size_t)b * 32 + c] = val;             // row-major [n][32]
    zrowb[(size_t)b * 32 + c] = f2bf(-val);     // negated bf16 for A-frags
  }

  if (blockIdx.x < 16) {                        // se + ebf: 16*256 codes
    int code = blockIdx.x * 256 + tid;
    float s = 0.f;
#pragma unroll
    for (int c = 0; c < 32; ++c) {
      float e = embed[(size_t)code * 32 + c];
      ebf[(size_t)code * 32 + c] = f2bf(e);
      s += e * e;                                // sequential like ref
    }
    se[code] = s;
  } else if (blockIdx.x == 16) {
    if (tid < 64) {
      int pn_i = tid >> 4;          // 0..3 -> pn = 1,2,4,8
      int o    = tid & 15;
      int pn   = 1 << pn_i;
      double scale = (double)pn / 16.0;
      double x  = (o + 0.5) * scale - 0.5;
      double x0 = floor(x);
      double tf = x - x0;
      float row[8];
#pragma unroll
      for (int h = 0; h < 8; ++h) row[h] = 0.f;
      const double A = -0.75;
#pragma unroll
      for (int off = -1; off <= 2; ++off) {
        double s = fabs(tf - (double)off);
        double cub;
        if (s <= 1.0)      cub = ((A + 2.0) * s - (A + 3.0)) * s * s + 1.0;
        else if (s < 2.0)  cub = (((s - 5.0) * s + 8.0) * s - 4.0) * A;
        else               cub = 0.0;
        int idx = (int)x0 + off;
        idx = min(max(idx, 0), pn - 1);
        row[idx] = (float)((double)row[idx] + cub);  // numpy f32 += f64
      }
#pragma unroll
      for (int h = 0; h < 8; ++h) tables[pn_i * 128 + o * 8 + h] = row[h];
    }
  } else if (blockIdx.x == 17) {
    keys0[tid] = ~0ull;                          // pn=1: N=256
  } else if (blockIdx.x >= 20 && blockIdx.x < 60) {
    loss_slots[(blockIdx.x - 20) * 256 + tid] = 0.f;   // 40*256 = 10240 zeros
  }
}

// ------------- fused scan: prefix-min thresholds + candidates + rescue ------
// block 256 = 4 waves x 32 points (2 frags/wave); grid (N/128, NVC).
// Pass order: window0 min-only, windows 1..NW-1 collect w/ prefix-min,
// window0 collected last with full-chunk min.
__global__ __launch_bounds__(256) void vq_scan_kernel(
    const short* __restrict__ zrowb, const short* __restrict__ ebf,
    const float* __restrict__ se, const float* __restrict__ zrow,
    const float* __restrict__ embed, unsigned long long* __restrict__ keys,
    int vchunk)
{
  __shared__ __align__(16) short elds[WIN * 40]; // padded stride 80B rows
  __shared__ float selds[WIN];
  __shared__ unsigned int clist[CAP];            // (nloc<<12) | v
  __shared__ unsigned long long lkey[128];       // per-point local best key
  __shared__ int ccnt;

  const int tid = threadIdx.x;
  const int lane = tid & 63, wave = tid >> 6;
  const int col = lane & 15, quad = lane >> 4;
  const int nblk = blockIdx.x * 128;
  const int nw = nblk + wave * 32;
  const int vbase = blockIdx.y * vchunk;

  if (tid < 128) lkey[tid] = ~0ull;
  if (tid == 0) ccnt = 0;

  // A-frags: one coalesced 16B load each from pre-negated bf16 z rows
  bf16x8 af[2];
#pragma unroll
  for (int f = 0; f < 2; ++f)
    af[f] = *(const bf16x8*)(zrowb + (size_t)(nw + f * 16 + col) * 32 + quad * 8);

  float mn[2][4];
#pragma unroll
  for (int f = 0; f < 2; ++f)
#pragma unroll
    for (int r = 0; r < 4; ++r) mn[f][r] = 3.4e38f;

  const int NW = vchunk / WIN;

  for (int pass = 0; pass <= NW; ++pass) {
    const int w0 = (pass == NW) ? 0 : pass * WIN;
    __syncthreads();
    {
      // stage window: 128 rows x 2 threads, full 32-short rows, 80B stride
      int row = tid >> 1, half = tid & 1;
      const bf16x8* src = (const bf16x8*)(ebf + (size_t)(vbase + w0 + row) * 32);
      bf16x8* dst = (bf16x8*)(elds + row * 40);
      dst[half * 2]     = src[half * 2];
      dst[half * 2 + 1] = src[half * 2 + 1];
      if (tid < WIN) selds[tid] = 0.5f * se[vbase + w0 + tid];  // *0.5 exact
    }
    __syncthreads();

    // thresholds: butterflied prefix-min + MARGIN (pass 0: disabled)
    float thr[2][4], tmax;
    if (pass == 0) {
#pragma unroll
      for (int f = 0; f < 2; ++f)
#pragma unroll
        for (int r = 0; r < 4; ++r) thr[f][r] = -3.4e38f;
      tmax = -3.4e38f;
    } else {
#pragma unroll
      for (int f = 0; f < 2; ++f)
#pragma unroll
        for (int r = 0; r < 4; ++r) {
          float m = mn[f][r];
          m = fminf(m, __shfl_xor(m, 1, 64));
          m = fminf(m, __shfl_xor(m, 2, 64));
          m = fminf(m, __shfl_xor(m, 4, 64));
          m = fminf(m, __shfl_xor(m, 8, 64));
          thr[f][r] = m + MARGIN_;
        }
      tmax = fmaxf(
          fmaxf(fmaxf(thr[0][0], thr[0][1]), fmaxf(thr[0][2], thr[0][3])),
          fmaxf(fmaxf(thr[1][0], thr[1][1]), fmaxf(thr[1][2], thr[1][3])));
    }

    for (int vv = 0; vv < WIN; vv += 16) {
      bf16x8 bf = *(const bf16x8*)(elds + (vv + col) * 40 + quad * 8);
      float sevh = selds[vv + col];
      f32x4 cin = {sevh, sevh, sevh, sevh};       // D = se/2 + (-z)*e
      f32x4 d0 = __builtin_amdgcn_mfma_f32_16x16x32_bf16(af[0], bf, cin, 0, 0, 0);
      f32x4 d1 = __builtin_amdgcn_mfma_f32_16x16x32_bf16(af[1], bf, cin, 0, 0, 0);
      // running per-point min (per-lane col-slice; butterflied at window tops)
#pragma unroll
      for (int r = 0; r < 4; ++r) {
        mn[0][r] = fminf(mn[0][r], d0[r]);
        mn[1][r] = fminf(mn[1][r], d1[r]);
      }
      // coarse gate: min of 8 vs max of 8 thrs (no false negatives)
      float a = min3f(d0[0], d0[1], d0[2]);
      float b = min3f(d0[3], d1[0], d1[1]);
      float c = min3f(d1[2], d1[3], a);
      if (fminf(b, c) <= tmax) {
        f32x4 dd[2] = {d0, d1};
#pragma unroll
        for (int f = 0; f < 2; ++f) {
#pragma unroll
          for (int r = 0; r < 4; ++r) {
            if (dd[f][r] <= thr[f][r]) {
              int nloc = wave * 32 + f * 16 + quad * 4 + r;
              int v = vbase + w0 + vv + col;
              int slot = atomicAdd(&ccnt, 1);
              if (slot < CAP) {
                clist[slot] = ((unsigned)nloc << 12) | (unsigned)v;
              } else {
                // overflow fallback: exact inline (ascending-c fp order)
                const float* zp = zrow + (size_t)(nblk + nloc) * 32;
                const float* ep = embed + (size_t)v * 32;
                float dot = 0.f, sz = 0.f;
#pragma unroll 1
                for (int i = 0; i < 32; ++i) {
                  float zc = zp[i];
                  dot = fmaf(zc, ep[i], dot);
                  sz  = fmaf(zc, zc, sz);
                }
                float d = fmaf(-2.0f, dot, sz) + se[v];
                atomicMin(&lkey[nloc],
                          ((unsigned long long)encf(d) << 32) | (unsigned)v);
              }
            }
          }
        }
      }
    }
  }

  // batch exact-fp32 rescue into LDS keys (identical fp order to r16)
  __syncthreads();
  int tot = min(ccnt, CAP);
  for (int j = tid; j < tot; j += 256) {
    unsigned cv = clist[j];
    int nloc = (int)(cv >> 12);
    int v = (int)(cv & 4095u);
    const float* zp = zrow + (size_t)(nblk + nloc) * 32;
    const float* ep = embed + (size_t)v * 32;
    float dot = 0.f, sz = 0.f;
#pragma unroll
    for (int i = 0; i < 32; ++i) {
      float zc = zp[i];
      dot = fmaf(zc, ep[i], dot);
      sz  = fmaf(zc, zc, sz);
    }
    float d = fmaf(-2.0f, dot, sz) + se[v];
    atomicMin(&lkey[nloc], ((unsigned long long)encf(d) << 32) | (unsigned)v);
  }
  __syncthreads();
  if (tid < 128) {
    unsigned long long k = lkey[tid];
    if (k != ~0ull) atomicMin(&keys[nblk + tid], k);   // 1 global atomic/pt
  }
}

// ---- upsample + f_rest update + loss + idx out + next-scale prep ----
// block = one (b,c) plane; blockIdx.x = b*32+c; tid = o*16+p
__global__ __launch_bounds__(256) void up_update_kernel(
    const float* __restrict__ embed, const unsigned long long* __restrict__ keys,
    const float* __restrict__ tbl, float* __restrict__ f_rest, int pn,
    float* __restrict__ zrow, short* __restrict__ zrowb,
    unsigned long long* __restrict__ keys_nb, int pn_next, int n_next,
    float* __restrict__ idx_out, float* __restrict__ loss_slot)
{
  __shared__ float sm[256];
  __shared__ float sm_e[64];
  const int tid = threadIdx.x;
  const int t = blockIdx.x * 256 + tid;
  const int p = tid & 15, o = tid >> 4;
  const int c = blockIdx.x & 31, b = blockIdx.x >> 5;
  const int pn2 = pn * pn;

  float pre = f_rest[t];
  sm[tid] = pre;
  if (tid < pn2) {
    int idx = keyidx(keys[b * pn2 + tid]);
    if (c == 0) idx_out[b * pn2 + tid] = (float)idx;
    sm_e[tid] = embed[(size_t)idx * 32 + c];
  }
  __syncthreads();

  // loss partial: recompute zavg from pre-update plane (== zrow exactly)
  float lsum = 0.f;
  if (tid < pn2) {
    int k = 16 / pn;
    int ph = tid / pn, pw = tid - ph * pn;
    float s = 0.f;
    for (int i = 0; i < k; ++i)
      for (int j = 0; j < k; ++j)
        s += sm[(ph * k + i) * 16 + (pw * k + j)];
    float zavg = s * (1.0f / (k * k));
    float d = sm_e[tid] - zavg;
    lsum = d * d;
  }
#pragma unroll
  for (int off = 32; off > 0; off >>= 1) lsum += __shfl_down(lsum, off, 64);
  if ((tid & 63) == 0)
    atomicAdd(loss_slot + ((blockIdx.x & 127) << 4), lsum);

  // bicubic upsample (ref: h-einsum first, then w)
  const float* Wo = tbl + o * 8;
  const float* Wp = tbl + p * 8;
  float acc = 0.f;
  for (int w = 0; w < pn; ++w) {
    float inner = 0.f;
    for (int h = 0; h < pn; ++h)
      inner = fmaf(Wo[h], sm_e[h * pn + w], inner);
    acc = fmaf(Wp[w], inner, acc);
  }
  float nr = pre - acc;
  f_rest[t] = nr;

  __syncthreads();
  sm[tid] = nr;
  __syncthreads();
  const int pnn2 = pn_next * pn_next;
  if (tid < pnn2) {
    int ph = tid / pn_next, pw = tid - ph * pn_next;
    int k = 16 / pn_next;
    float s = 0.f;
    for (int i = 0; i < k; ++i)
      for (int j = 0; j < k; ++j)
        s += sm[(ph * k + i) * 16 + (pw * k + j)];
    float zavg = s * (1.0f / (k * k));
    size_t nn = (size_t)(b * pnn2 + tid);
    zrow[nn * 32 + c]  = zavg;          // exact f32 for rescue/loss
    zrowb[nn * 32 + c] = f2bf(-zavg);   // negated bf16 A-frag source
  }
  if (t < n_next) {                // reset ping-pong keys for next scale
    keys_nb[t] = ~0ull;
  }
}

// -- final scale (pn=16): out = (z - f_rest) + embed[idx], idx out, loss --
__global__ __launch_bounds__(256) void final_add_kernel(
    const float* __restrict__ z, const float* __restrict__ f_rest,
    const float* __restrict__ embed, const unsigned long long* __restrict__ keys,
    float* __restrict__ f_hat, float* __restrict__ idx_out,
    float* __restrict__ loss_slot)
{
  const int tid = threadIdx.x;
  const int t = blockIdx.x * 256 + tid;
  const int c = blockIdx.x & 31, b = blockIdx.x >> 5;
  const int n = b * 256 + tid;
  int idx = keyidx(keys[n]);
  if (c == 0) idx_out[n] = (float)idx;
  float e = embed[(size_t)idx * 32 + c];
  float fr = f_rest[t];
  f_hat[t] = (z[t] - fr) + e;   // f_hat = sum of zq (err ~1e-6)
  float d = e - fr;             // fr == zavg at pn=16 bit-exactly
  float lsum = d * d;
#pragma unroll
  for (int off = 32; off > 0; off >>= 1) lsum += __shfl_down(lsum, off, 64);
  if ((tid & 63) == 0)
    atomicAdd(loss_slot + ((blockIdx.x & 127) << 4), lsum);
}

// ------------- final loss reduce: 5 scales x 128 padded slots -------------
__global__ __launch_bounds__(128) void loss_final_kernel(
    const float* __restrict__ loss_slots, float* __restrict__ out_loss)
{
  __shared__ float lred[2];
  const int tid = threadIdx.x;   // 128 threads = 2 waves
  const float numel[5] = {8192.f, 32768.f, 131072.f, 524288.f, 2097152.f};
  float tot = 0.f;
  for (int s = 0; s < 5; ++s) {
    float x = loss_slots[s * 2048 + tid * 16];
#pragma unroll
    for (int off = 32; off > 0; off >>= 1) x += __shfl_down(x, off, 64);
    if ((tid & 63) == 0) lred[tid >> 6] = x;
    __syncthreads();
    if (tid == 0) {
      float m = (lred[0] + lred[1]) / numel[s];
      tot += 0.25f * m + m;        // beta*mean + mean
    }
    __syncthreads();
  }
  if (tid == 0) out_loss[0] = tot / 5.f;
}

// =========================== host launcher ===========================
extern "C" void kernel_launch(void* const* d_in, const int* in_sizes, int n_in,
                              void* d_out, int out_size, void* d_ws, size_t ws_size,
                              hipStream_t stream)
{
  const float* z     = (const float*)d_in[0];
  const float* embed = (const float*)d_in[1];
  float* out = (float*)d_out;
  float* ws  = (float*)d_ws;

  // ws layout (float slots), total 5487104 floats ~= 20.9 MiB
  float* f_rest  = ws;                                   // 2097152
  float* zrow    = ws + 2097152;                         // [65536][32] f32
  short* zrowb   = (short*)(ws + 4194304);               // [65536][32] bf16(-z)
  short* ebf     = (short*)(ws + 5242880);               // 131072 shorts
  float* se      = ws + 5308416;                         // 4096
  unsigned long long* keys0 = (unsigned long long*)(ws + 5312512); // 65536 u64
  unsigned long long* keys1 = (unsigned long long*)(ws + 5443584); // 16384 u64
  float* loss_slots = ws + 5476352;                      // 5*128*16 = 10240
  float* tables     = ws + 5486592;                      // 512

  unsigned long long* keysb[2] = {keys0, keys1};

  setup_kernel<<<NTOT / 256, 256, 0, stream>>>(z, embed, f_rest, zrow, zrowb,
                                               ebf, se, tables, loss_slots,
                                               keys0);

  const int PN[5]  = {1, 2, 4, 8, 16};
  // chunks: vchunk = V_/NVC (multiple of WIN). Bigger chunks at large pn for
  // threshold quality; small pn are latency-dominated anyway.
  const int NVC[5] = {32, 32, 16, 8, 4};
  int idx_off = NTOT;
  for (int i = 0; i < 5; ++i) {
    int pn = PN[i];
    int N  = B_ * pn * pn;
    int vchunk = V_ / NVC[i];
    unsigned long long* kb = keysb[i & 1];
    dim3 g(N / 128, NVC[i]);
    vq_scan_kernel<<<g, 256, 0, stream>>>(zrowb, ebf, se, zrow, embed,
                                          kb, vchunk);
    if (i < 4) {
      int pnn = PN[i + 1];
      up_update_kernel<<<NTOT / 256, 256, 0, stream>>>(
          embed, kb, tables + i * 128, f_rest, pn,
          zrow, zrowb, keysb[(i + 1) & 1],
          pnn, B_ * pnn * pnn, out + idx_off, loss_slots + i * 2048);
    } else {
      final_add_kernel<<<NTOT / 256, 256, 0, stream>>>(
          z, f_rest, embed, kb, out, out + idx_off, loss_slots + 4 * 2048);
    }
    idx_off += N;
  }
  loss_final_kernel<<<1, 128, 0, stream>>>(loss_slots, out + 2184448);
}

// Round 5
// 495.377 us; speedup vs baseline: 10.1145x; 1.0017x over previous
//
#include <hip/hip_runtime.h>
#include <hip/hip_bf16.h>
#include <cstdint>
#include <cstddef>

// MultiScaleQuantizer: z (256,32,16,16) fp32, embed (4096,32) fp32.
// Outputs concat (fp32): f_hat (2097152), idx@pn=1..16 (87296), loss (1).
//
// r21: fused scan, lean two-pass schedule. r20 validated chunk-min+MARGIN
// threshold quality (WRITE_SIZE flat = no candidate blowup) but its schedule
// was heavy (per-window butterflies + gate+min in every pass = 8.7ns/window
// vs r16's 4ns). r21 stages the whole 512-code chunk in LDS ONCE, then:
//   pass 1: r16's lean phaseA loop (2 MFMA + 8 fmin / slab, no gate)
//   one butterfly -> per-point chunk-min + MARGIN thresholds
//   pass 2: r16's phaseB collect loop re-reading the same LDS windows.
// Correct: for exact argmin v* in this block's chunk, d_bf16(v*) <=
// chunkmin + 2eps (2eps~0.1 << MARGIN=1.0) -> always collected; exact-fp32
// rescue (identical fp order) + atomicMin key -> identical winner/tie-break.
// vs r16 A+B: staging halved, barriers 3/block (was ~8), smin round-trip and
// 5 launches deleted, same slab count, same lean loops, zrowb af 16B loads.

#define B_   256
#define V_   4096
#define NTOT 2097152   // 256*32*16*16
#define WIN  128
#define CHUNK 512      // codes staged per block (4 windows)
#define CAP  2048      // candidate list capacity per block (u32 entries)
#define MARGIN_ 1.0f

using bf16x8 = __attribute__((ext_vector_type(8))) short;
using f32x4  = __attribute__((ext_vector_type(4))) float;

__device__ inline short f2bf(float f) {
  __hip_bfloat16 h = __float2bfloat16(f);
  return *reinterpret_cast<short*>(&h);
}
__device__ inline unsigned encf(float f) {        // monotone fp32 -> u32
  unsigned u = __float_as_uint(f);
  return (u & 0x80000000u) ? ~u : (u | 0x80000000u);
}
__device__ inline int keyidx(unsigned long long k) {  // decode + clamp (safety)
  int i = (int)(unsigned)(k & 0xffffffffull);
  return min(max(i, 0), V_ - 1);
}
__device__ inline float min3f(float a, float b, float c) {
  float d;
  asm("v_min3_f32 %0, %1, %2, %3" : "=v"(d) : "v"(a), "v"(b), "v"(c));
  return d;
}

// ---- setup: f_rest=z, zrow/zrowb@pn1, ebf, se, tables, inits ----
// block = one (b,c) plane; blockIdx.x = b*32+c
__global__ __launch_bounds__(256) void setup_kernel(
    const float* __restrict__ z, const float* __restrict__ embed,
    float* __restrict__ f_rest, float* __restrict__ zrow,
    short* __restrict__ zrowb, short* __restrict__ ebf,
    float* __restrict__ se, float* __restrict__ tables,
    float* __restrict__ loss_slots, unsigned long long* __restrict__ keys0)
{
  const int tid = threadIdx.x;
  const int t = blockIdx.x * 256 + tid;
  float v = z[t];
  f_rest[t] = v;

  __shared__ float sm[256];
  sm[tid] = v;
  __syncthreads();
  if (tid == 0) {
    float s = 0.f;
    for (int i = 0; i < 256; ++i) s += sm[i];   // ref's linear i,j order
    int c = blockIdx.x & 31, b = blockIdx.x >> 5;
    float val = s * (1.0f / 256.0f);
    zrow[(size_t)b * 32 + c] = val;             // row-major [n][32]
    zrowb[(size_t)b * 32 + c] = f2bf(-val);     // negated bf16 for A-frags
  }

  if (blockIdx.x < 16) {                        // se + ebf: 16*256 codes
    int code = blockIdx.x * 256 + tid;
    float s = 0.f;
#pragma unroll
    for (int c = 0; c < 32; ++c) {
      float e = embed[(size_t)code * 32 + c];
      ebf[(size_t)code * 32 + c] = f2bf(e);
      s += e * e;                                // sequential like ref
    }
    se[code] = s;
  } else if (blockIdx.x == 16) {
    if (tid < 64) {
      int pn_i = tid >> 4;          // 0..3 -> pn = 1,2,4,8
      int o    = tid & 15;
      int pn   = 1 << pn_i;
      double scale = (double)pn / 16.0;
      double x  = (o + 0.5) * scale - 0.5;
      double x0 = floor(x);
      double tf = x - x0;
      float row[8];
#pragma unroll
      for (int h = 0; h < 8; ++h) row[h] = 0.f;
      const double A = -0.75;
#pragma unroll
      for (int off = -1; off <= 2; ++off) {
        double s = fabs(tf - (double)off);
        double cub;
        if (s <= 1.0)      cub = ((A + 2.0) * s - (A + 3.0)) * s * s + 1.0;
        else if (s < 2.0)  cub = (((s - 5.0) * s + 8.0) * s - 4.0) * A;
        else               cub = 0.0;
        int idx = (int)x0 + off;
        idx = min(max(idx, 0), pn - 1);
        row[idx] = (float)((double)row[idx] + cub);  // numpy f32 += f64
      }
#pragma unroll
      for (int h = 0; h < 8; ++h) tables[pn_i * 128 + o * 8 + h] = row[h];
    }
  } else if (blockIdx.x == 17) {
    keys0[tid] = ~0ull;                          // pn=1: N=256
  } else if (blockIdx.x >= 20 && blockIdx.x < 60) {
    loss_slots[(blockIdx.x - 20) * 256 + tid] = 0.f;   // 40*256 = 10240 zeros
  }
}

// ---- fused scan: stage chunk once; pass1 min; butterfly; pass2 collect ----
// block 256 = 4 waves x 32 points (2 frags/wave); grid (N/128, V/CHUNK).
__global__ __launch_bounds__(256) void vq_scan_kernel(
    const short* __restrict__ zrowb, const short* __restrict__ ebf,
    const float* __restrict__ se, const float* __restrict__ zrow,
    const float* __restrict__ embed, unsigned long long* __restrict__ keys)
{
  __shared__ __align__(16) short elds[CHUNK * 40]; // padded 80B-stride rows
  __shared__ float selds[CHUNK];
  __shared__ unsigned int clist[CAP];              // (nloc<<12) | v
  __shared__ unsigned long long lkey[128];         // per-point best key
  __shared__ int ccnt;

  const int tid = threadIdx.x;
  const int lane = tid & 63, wave = tid >> 6;
  const int col = lane & 15, quad = lane >> 4;
  const int nblk = blockIdx.x * 128;
  const int nw = nblk + wave * 32;
  const int vbase = blockIdx.y * CHUNK;

  if (tid < 128) lkey[tid] = ~0ull;
  if (tid == 0) ccnt = 0;

  // A-frags: one coalesced 16B load each from pre-negated bf16 z rows
  bf16x8 af[2];
#pragma unroll
  for (int f = 0; f < 2; ++f)
    af[f] = *(const bf16x8*)(zrowb + (size_t)(nw + f * 16 + col) * 32 + quad * 8);

  // stage whole chunk: 512 rows; each thread stages 2 full rows (4x b128)
#pragma unroll
  for (int rr = 0; rr < 2; ++rr) {
    int row = tid + rr * 256;
    const bf16x8* src = (const bf16x8*)(ebf + (size_t)(vbase + row) * 32);
    bf16x8* dst = (bf16x8*)(elds + row * 40);
    dst[0] = src[0]; dst[1] = src[1]; dst[2] = src[2]; dst[3] = src[3];
    selds[row] = 0.5f * se[vbase + row];       // *0.5 exact
  }
  __syncthreads();

  // ---- pass 1: lean min-only (r16 phaseA loop) ----
  float mn[2][4];
#pragma unroll
  for (int f = 0; f < 2; ++f)
#pragma unroll
    for (int r = 0; r < 4; ++r) mn[f][r] = 3.4e38f;

  for (int vv = 0; vv < CHUNK; vv += 16) {
    bf16x8 bf = *(const bf16x8*)(elds + (vv + col) * 40 + quad * 8);
    float sevh = selds[vv + col];
    f32x4 cin = {sevh, sevh, sevh, sevh};       // D = se/2 + (-z)*e
    f32x4 d0 = __builtin_amdgcn_mfma_f32_16x16x32_bf16(af[0], bf, cin, 0, 0, 0);
    f32x4 d1 = __builtin_amdgcn_mfma_f32_16x16x32_bf16(af[1], bf, cin, 0, 0, 0);
#pragma unroll
    for (int r = 0; r < 4; ++r) {
      mn[0][r] = fminf(mn[0][r], d0[r]);
      mn[1][r] = fminf(mn[1][r], d1[r]);
    }
  }

  // ---- one butterfly: per-point chunk-min + MARGIN ----
  float thr[2][4];
#pragma unroll
  for (int f = 0; f < 2; ++f)
#pragma unroll
    for (int r = 0; r < 4; ++r) {
      float m = mn[f][r];
      m = fminf(m, __shfl_xor(m, 1, 64));
      m = fminf(m, __shfl_xor(m, 2, 64));
      m = fminf(m, __shfl_xor(m, 4, 64));
      m = fminf(m, __shfl_xor(m, 8, 64));
      thr[f][r] = m + MARGIN_;
    }
  float tmax = fmaxf(
      fmaxf(fmaxf(thr[0][0], thr[0][1]), fmaxf(thr[0][2], thr[0][3])),
      fmaxf(fmaxf(thr[1][0], thr[1][1]), fmaxf(thr[1][2], thr[1][3])));

  // ---- pass 2: collect (r16 phaseB loop, same LDS, no re-stage) ----
  for (int vv = 0; vv < CHUNK; vv += 16) {
    bf16x8 bf = *(const bf16x8*)(elds + (vv + col) * 40 + quad * 8);
    float sevh = selds[vv + col];
    f32x4 cin = {sevh, sevh, sevh, sevh};
    f32x4 dd[2];
    dd[0] = __builtin_amdgcn_mfma_f32_16x16x32_bf16(af[0], bf, cin, 0, 0, 0);
    dd[1] = __builtin_amdgcn_mfma_f32_16x16x32_bf16(af[1], bf, cin, 0, 0, 0);
    // coarse gate: min of 8 vs max of 8 thrs (no false negatives)
    float a = min3f(dd[0][0], dd[0][1], dd[0][2]);
    float b = min3f(dd[0][3], dd[1][0], dd[1][1]);
    float c = min3f(dd[1][2], dd[1][3], a);
    if (fminf(b, c) <= tmax) {
#pragma unroll
      for (int f = 0; f < 2; ++f) {
#pragma unroll
        for (int r = 0; r < 4; ++r) {
          if (dd[f][r] <= thr[f][r]) {
            int nloc = wave * 32 + f * 16 + quad * 4 + r;
            int v = vbase + vv + col;
            int slot = atomicAdd(&ccnt, 1);
            if (slot < CAP) {
              clist[slot] = ((unsigned)nloc << 12) | (unsigned)v;
            } else {
              // overflow fallback: exact inline (ascending-c fp order)
              const float* zp = zrow + (size_t)(nblk + nloc) * 32;
              const float* ep = embed + (size_t)v * 32;
              float dot = 0.f, sz = 0.f;
#pragma unroll 1
              for (int i = 0; i < 32; ++i) {
                float zc = zp[i];
                dot = fmaf(zc, ep[i], dot);
                sz  = fmaf(zc, zc, sz);
              }
              float d = fmaf(-2.0f, dot, sz) + se[v];
              atomicMin(&lkey[nloc],
                        ((unsigned long long)encf(d) << 32) | (unsigned)v);
            }
          }
        }
      }
    }
  }

  // batch exact-fp32 rescue into LDS keys (identical fp order to r16)
  __syncthreads();
  int tot = min(ccnt, CAP);
  for (int j = tid; j < tot; j += 256) {
    unsigned cv = clist[j];
    int nloc = (int)(cv >> 12);
    int v = (int)(cv & 4095u);
    const float* zp = zrow + (size_t)(nblk + nloc) * 32;
    const float* ep = embed + (size_t)v * 32;
    float dot = 0.f, sz = 0.f;
#pragma unroll
    for (int i = 0; i < 32; ++i) {
      float zc = zp[i];
      dot = fmaf(zc, ep[i], dot);
      sz  = fmaf(zc, zc, sz);
    }
    float d = fmaf(-2.0f, dot, sz) + se[v];
    atomicMin(&lkey[nloc], ((unsigned long long)encf(d) << 32) | (unsigned)v);
  }
  __syncthreads();
  if (tid < 128) {
    unsigned long long k = lkey[tid];
    if (k != ~0ull) atomicMin(&keys[nblk + tid], k);   // 1 global atomic/pt
  }
}

// ---- upsample + f_rest update + loss + idx out + next-scale prep ----
// block = one (b,c) plane; blockIdx.x = b*32+c; tid = o*16+p
__global__ __launch_bounds__(256) void up_update_kernel(
    const float* __restrict__ embed, const unsigned long long* __restrict__ keys,
    const float* __restrict__ tbl, float* __restrict__ f_rest, int pn,
    float* __restrict__ zrow, short* __restrict__ zrowb,
    unsigned long long* __restrict__ keys_nb, int pn_next, int n_next,
    float* __restrict__ idx_out, float* __restrict__ loss_slot)
{
  __shared__ float sm[256];
  __shared__ float sm_e[64];
  const int tid = threadIdx.x;
  const int t = blockIdx.x * 256 + tid;
  const int p = tid & 15, o = tid >> 4;
  const int c = blockIdx.x & 31, b = blockIdx.x >> 5;
  const int pn2 = pn * pn;

  float pre = f_rest[t];
  sm[tid] = pre;
  if (tid < pn2) {
    int idx = keyidx(keys[b * pn2 + tid]);
    if (c == 0) idx_out[b * pn2 + tid] = (float)idx;
    sm_e[tid] = embed[(size_t)idx * 32 + c];
  }
  __syncthreads();

  // loss partial: recompute zavg from pre-update plane (== zrow exactly)
  float lsum = 0.f;
  if (tid < pn2) {
    int k = 16 / pn;
    int ph = tid / pn, pw = tid - ph * pn;
    float s = 0.f;
    for (int i = 0; i < k; ++i)
      for (int j = 0; j < k; ++j)
        s += sm[(ph * k + i) * 16 + (pw * k + j)];
    float zavg = s * (1.0f / (k * k));
    float d = sm_e[tid] - zavg;
    lsum = d * d;
  }
#pragma unroll
  for (int off = 32; off > 0; off >>= 1) lsum += __shfl_down(lsum, off, 64);
  if ((tid & 63) == 0)
    atomicAdd(loss_slot + ((blockIdx.x & 127) << 4), lsum);

  // bicubic upsample (ref: h-einsum first, then w)
  const float* Wo = tbl + o * 8;
  const float* Wp = tbl + p * 8;
  float acc = 0.f;
  for (int w = 0; w < pn; ++w) {
    float inner = 0.f;
    for (int h = 0; h < pn; ++h)
      inner = fmaf(Wo[h], sm_e[h * pn + w], inner);
    acc = fmaf(Wp[w], inner, acc);
  }
  float nr = pre - acc;
  f_rest[t] = nr;

  __syncthreads();
  sm[tid] = nr;
  __syncthreads();
  const int pnn2 = pn_next * pn_next;
  if (tid < pnn2) {
    int ph = tid / pn_next, pw = tid - ph * pn_next;
    int k = 16 / pn_next;
    float s = 0.f;
    for (int i = 0; i < k; ++i)
      for (int j = 0; j < k; ++j)
        s += sm[(ph * k + i) * 16 + (pw * k + j)];
    float zavg = s * (1.0f / (k * k));
    size_t nn = (size_t)(b * pnn2 + tid);
    zrow[nn * 32 + c]  = zavg;          // exact f32 for rescue/loss
    zrowb[nn * 32 + c] = f2bf(-zavg);   // negated bf16 A-frag source
  }
  if (t < n_next) {                // reset ping-pong keys for next scale
    keys_nb[t] = ~0ull;
  }
}

// -- final scale (pn=16): out = (z - f_rest) + embed[idx], idx out, loss --
__global__ __launch_bounds__(256) void final_add_kernel(
    const float* __restrict__ z, const float* __restrict__ f_rest,
    const float* __restrict__ embed, const unsigned long long* __restrict__ keys,
    float* __restrict__ f_hat, float* __restrict__ idx_out,
    float* __restrict__ loss_slot)
{
  const int tid = threadIdx.x;
  const int t = blockIdx.x * 256 + tid;
  const int c = blockIdx.x & 31, b = blockIdx.x >> 5;
  const int n = b * 256 + tid;
  int idx = keyidx(keys[n]);
  if (c == 0) idx_out[n] = (float)idx;
  float e = embed[(size_t)idx * 32 + c];
  float fr = f_rest[t];
  f_hat[t] = (z[t] - fr) + e;   // f_hat = sum of zq (err ~1e-6)
  float d = e - fr;             // fr == zavg at pn=16 bit-exactly
  float lsum = d * d;
#pragma unroll
  for (int off = 32; off > 0; off >>= 1) lsum += __shfl_down(lsum, off, 64);
  if ((tid & 63) == 0)
    atomicAdd(loss_slot + ((blockIdx.x & 127) << 4), lsum);
}

// ------------- final loss reduce: 5 scales x 128 padded slots -------------
__global__ __launch_bounds__(128) void loss_final_kernel(
    const float* __restrict__ loss_slots, float* __restrict__ out_loss)
{
  __shared__ float lred[2];
  const int tid = threadIdx.x;   // 128 threads = 2 waves
  const float numel[5] = {8192.f, 32768.f, 131072.f, 524288.f, 2097152.f};
  float tot = 0.f;
  for (int s = 0; s < 5; ++s) {
    float x = loss_slots[s * 2048 + tid * 16];
#pragma unroll
    for (int off = 32; off > 0; off >>= 1) x += __shfl_down(x, off, 64);
    if ((tid & 63) == 0) lred[tid >> 6] = x;
    __syncthreads();
    if (tid == 0) {
      float m = (lred[0] + lred[1]) / numel[s];
      tot += 0.25f * m + m;        // beta*mean + mean
    }
    __syncthreads();
  }
  if (tid == 0) out_loss[0] = tot / 5.f;
}

// =========================== host launcher ===========================
extern "C" void kernel_launch(void* const* d_in, const int* in_sizes, int n_in,
                              void* d_out, int out_size, void* d_ws, size_t ws_size,
                              hipStream_t stream)
{
  const float* z     = (const float*)d_in[0];
  const float* embed = (const float*)d_in[1];
  float* out = (float*)d_out;
  float* ws  = (float*)d_ws;

  // ws layout (float slots), total 5487104 floats ~= 20.9 MiB
  float* f_rest  = ws;                                   // 2097152
  float* zrow    = ws + 2097152;                         // [65536][32] f32
  short* zrowb   = (short*)(ws + 4194304);               // [65536][32] bf16(-z)
  short* ebf     = (short*)(ws + 5242880);               // 131072 shorts
  float* se      = ws + 5308416;                         // 4096
  unsigned long long* keys0 = (unsigned long long*)(ws + 5312512); // 65536 u64
  unsigned long long* keys1 = (unsigned long long*)(ws + 5443584); // 16384 u64
  float* loss_slots = ws + 5476352;                      // 5*128*16 = 10240
  float* tables     = ws + 5486592;                      // 512

  unsigned long long* keysb[2] = {keys0, keys1};

  setup_kernel<<<NTOT / 256, 256, 0, stream>>>(z, embed, f_rest, zrow, zrowb,
                                               ebf, se, tables, loss_slots,
                                               keys0);

  const int PN[5] = {1, 2, 4, 8, 16};
  int idx_off = NTOT;
  for (int i = 0; i < 5; ++i) {
    int pn = PN[i];
    int N  = B_ * pn * pn;
    unsigned long long* kb = keysb[i & 1];
    dim3 g(N / 128, V_ / CHUNK);
    vq_scan_kernel<<<g, 256, 0, stream>>>(zrowb, ebf, se, zrow, embed, kb);
    if (i < 4) {
      int pnn = PN[i + 1];
      up_update_kernel<<<NTOT / 256, 256, 0, stream>>>(
          embed, kb, tables + i * 128, f_rest, pn,
          zrow, zrowb, keysb[(i + 1) & 1],
          pnn, B_ * pnn * pnn, out + idx_off, loss_slots + i * 2048);
    } else {
      final_add_kernel<<<NTOT / 256, 256, 0, stream>>>(
          z, f_rest, embed, kb, out, out + idx_off, loss_slots + 4 * 2048);
    }
    idx_off += N;
  }
  loss_final_kernel<<<1, 128, 0, stream>>>(loss_slots, out + 2184448);
}

// Round 6
// 435.597 us; speedup vs baseline: 11.5025x; 1.1372x over previous
//
#include <hip/hip_runtime.h>
#include <hip/hip_bf16.h>
#include <cstdint>
#include <cstddef>

// MultiScaleQuantizer: z (256,32,16,16) fp32, embed (4096,32) fp32.
// Outputs concat (fp32): f_hat (2097152), idx@pn=1..16 (87296), loss (1).
//
// r22 = r16's proven two-phase scheme (global-min thresholds; every fused /
// subset-threshold variant r17-r21 lost) with ONE structural change:
// M-per-wave 32 -> 64 (4 A-frags). Per inner iter: 2 B-slabs x 4 A-frags =
// 8 MFMA per (2 ds_read_b128 + 2 ds_read_b32). Rationale: per-CU audit of
// r16-r21 counters (MfmaUtil ~9%, VALUBusy 45-55%, 6 extra cyc/b128
// conflict) shows the LDS pipe is the oversubscribed unit (~24 LDS-cyc per
// 2 MFMA per wave, x12 waves/CU vs 4 SIMDs). Halving LDS-per-MFMA + 2x ILP
// attacks that directly. A-frags load as one coalesced 16B read each from
// pre-negated bf16 zrowb (r19/r20/r21-verified), killing the per-block
// 64-strided-load + f2bf setup. min3-slab-merged mins keep VALU at 2/MFMA.

#define B_   256
#define V_   4096
#define NTOT 2097152   // 256*32*16*16
#define WIN  128       // codebook window staged in LDS
#define CAP  1024      // candidate list capacity per block (u64 entries)
#define MARGIN_ 1.0f

using bf16x8 = __attribute__((ext_vector_type(8))) short;
using f32x4  = __attribute__((ext_vector_type(4))) float;

__device__ inline short f2bf(float f) {
  __hip_bfloat16 h = __float2bfloat16(f);
  return *reinterpret_cast<short*>(&h);
}
__device__ inline unsigned encf(float f) {        // monotone fp32 -> u32
  unsigned u = __float_as_uint(f);
  return (u & 0x80000000u) ? ~u : (u | 0x80000000u);
}
__device__ inline float decf(unsigned u) {
  unsigned b = (u & 0x80000000u) ? (u ^ 0x80000000u) : ~u;
  return __uint_as_float(b);
}
__device__ inline int keyidx(unsigned long long k) {  // decode + clamp (safety)
  int i = (int)(unsigned)(k & 0xffffffffull);
  return min(max(i, 0), V_ - 1);
}
__device__ inline float min3f(float a, float b, float c) {
  float d;
  asm("v_min3_f32 %0, %1, %2, %3" : "=v"(d) : "v"(a), "v"(b), "v"(c));
  return d;
}

// ---- setup: f_rest=z, zrow/zrowb@pn1, ebf, se, tables, inits ----
// block = one (b,c) plane; blockIdx.x = b*32+c
__global__ __launch_bounds__(256) void setup_kernel(
    const float* __restrict__ z, const float* __restrict__ embed,
    float* __restrict__ f_rest, float* __restrict__ zrow,
    short* __restrict__ zrowb, short* __restrict__ ebf,
    float* __restrict__ se, float* __restrict__ tables,
    float* __restrict__ loss_slots, unsigned long long* __restrict__ keys0,
    unsigned int* __restrict__ smin0)
{
  const int tid = threadIdx.x;
  const int t = blockIdx.x * 256 + tid;
  float v = z[t];
  f_rest[t] = v;

  __shared__ float sm[256];
  sm[tid] = v;
  __syncthreads();
  if (tid == 0) {
    float s = 0.f;
    for (int i = 0; i < 256; ++i) s += sm[i];   // ref's linear i,j order
    int c = blockIdx.x & 31, b = blockIdx.x >> 5;
    float val = s * (1.0f / 256.0f);
    zrow[(size_t)b * 32 + c] = val;             // row-major [n][32]
    zrowb[(size_t)b * 32 + c] = f2bf(-val);     // negated bf16 for A-frags
  }

  if (blockIdx.x < 16) {                        // se + ebf: 16*256 codes
    int code = blockIdx.x * 256 + tid;
    float s = 0.f;
#pragma unroll
    for (int c = 0; c < 32; ++c) {
      float e = embed[(size_t)code * 32 + c];
      ebf[(size_t)code * 32 + c] = f2bf(e);
      s += e * e;                                // sequential like ref
    }
    se[code] = s;
  } else if (blockIdx.x == 16) {
    if (tid < 64) {
      int pn_i = tid >> 4;          // 0..3 -> pn = 1,2,4,8
      int o    = tid & 15;
      int pn   = 1 << pn_i;
      double scale = (double)pn / 16.0;
      double x  = (o + 0.5) * scale - 0.5;
      double x0 = floor(x);
      double tf = x - x0;
      float row[8];
#pragma unroll
      for (int h = 0; h < 8; ++h) row[h] = 0.f;
      const double A = -0.75;
#pragma unroll
      for (int off = -1; off <= 2; ++off) {
        double s = fabs(tf - (double)off);
        double cub;
        if (s <= 1.0)      cub = ((A + 2.0) * s - (A + 3.0)) * s * s + 1.0;
        else if (s < 2.0)  cub = (((s - 5.0) * s + 8.0) * s - 4.0) * A;
        else               cub = 0.0;
        int idx = (int)x0 + off;
        idx = min(max(idx, 0), pn - 1);
        row[idx] = (float)((double)row[idx] + cub);  // numpy f32 += f64
      }
#pragma unroll
      for (int h = 0; h < 8; ++h) tables[pn_i * 128 + o * 8 + h] = row[h];
    }
  } else if (blockIdx.x == 17) {
    keys0[tid] = ~0ull;                          // pn=1: N=256
    smin0[tid] = 0xFFFFFFFFu;
  } else if (blockIdx.x >= 20 && blockIdx.x < 60) {
    loss_slots[(blockIdx.x - 20) * 256 + tid] = 0.f;   // 40*256 = 10240 zeros
  }
}

// ------- phase A: MFMA scan -> per-point min of s = se/2 - z.e -------------
// block 256 = 4 waves x 64 points (4 frags/wave); grid (N/256, NVC).
__global__ __launch_bounds__(256) void vq_phaseA_kernel(
    const short* __restrict__ zrowb, const short* __restrict__ ebf,
    const float* __restrict__ se, unsigned int* __restrict__ smin,
    int vchunk)
{
  __shared__ __align__(16) short elds[WIN * 40]; // padded 80B-stride rows
  __shared__ float selds[WIN];

  const int tid = threadIdx.x;
  const int lane = tid & 63, wave = tid >> 6;
  const int col = lane & 15, quad = lane >> 4;
  const int nw = blockIdx.x * 256 + wave * 64;
  const int vbase = blockIdx.y * vchunk;

  // A-frags: one coalesced 16B load each from pre-negated bf16 z rows
  bf16x8 af[4];
#pragma unroll
  for (int f = 0; f < 4; ++f)
    af[f] = *(const bf16x8*)(zrowb + (size_t)(nw + f * 16 + col) * 32 + quad * 8);

  float mn[4][4];
#pragma unroll
  for (int f = 0; f < 4; ++f)
#pragma unroll
    for (int r = 0; r < 4; ++r) mn[f][r] = 3.4e38f;

  for (int w0 = 0; w0 < vchunk; w0 += WIN) {
    __syncthreads();
    {
      // 128 rows x 2 threads; each thread stores 2 bf16x8 = full 32-short row
      int row = tid >> 1, half = tid & 1;
      const bf16x8* src = (const bf16x8*)(ebf + (size_t)(vbase + w0 + row) * 32);
      bf16x8* dst = (bf16x8*)(elds + row * 40);
      dst[half * 2]     = src[half * 2];
      dst[half * 2 + 1] = src[half * 2 + 1];
      if (tid < WIN) selds[tid] = 0.5f * se[vbase + w0 + tid];  // *0.5 exact
    }
    __syncthreads();
#pragma unroll 2
    for (int vv = 0; vv < WIN; vv += 32) {       // 2 slabs x 4 frags = 8 MFMA
      bf16x8 bfA = *(const bf16x8*)(elds + (vv + col) * 40 + quad * 8);
      bf16x8 bfB = *(const bf16x8*)(elds + (vv + 16 + col) * 40 + quad * 8);
      float sa = selds[vv + col], sb = selds[vv + 16 + col];
      f32x4 cinA = {sa, sa, sa, sa};
      f32x4 cinB = {sb, sb, sb, sb};
      f32x4 da[4], db[4];
#pragma unroll
      for (int f = 0; f < 4; ++f)
        da[f] = __builtin_amdgcn_mfma_f32_16x16x32_bf16(af[f], bfA, cinA, 0, 0, 0);
#pragma unroll
      for (int f = 0; f < 4; ++f)
        db[f] = __builtin_amdgcn_mfma_f32_16x16x32_bf16(af[f], bfB, cinB, 0, 0, 0);
#pragma unroll
      for (int f = 0; f < 4; ++f)
#pragma unroll
        for (int r = 0; r < 4; ++r)
          mn[f][r] = min3f(mn[f][r], da[f][r], db[f][r]);
    }
  }
  // cross-col min via shuffle butterfly
#pragma unroll
  for (int f = 0; f < 4; ++f)
#pragma unroll
    for (int r = 0; r < 4; ++r) {
      float m = mn[f][r];
      m = fminf(m, __shfl_xor(m, 1, 64));
      m = fminf(m, __shfl_xor(m, 2, 64));
      m = fminf(m, __shfl_xor(m, 4, 64));
      m = fminf(m, __shfl_xor(m, 8, 64));
      mn[f][r] = m;
    }
  if (col == 0) {
#pragma unroll
    for (int f = 0; f < 4; ++f)
#pragma unroll
      for (int r = 0; r < 4; ++r)
        atomicMin(&smin[nw + f * 16 + quad * 4 + r], encf(mn[f][r]));
  }
}

// -------- phase B: MFMA re-scan; candidates -> LDS list -> batch rescue -----
__global__ __launch_bounds__(256) void vq_phaseB_kernel(
    const short* __restrict__ zrowb, const short* __restrict__ ebf,
    const float* __restrict__ se, const unsigned int* __restrict__ smin,
    const float* __restrict__ zrow, const float* __restrict__ embed,
    unsigned long long* __restrict__ keys, int vchunk, int nmax)
{
  __shared__ __align__(16) short elds[WIN * 40];
  __shared__ float selds[WIN];
  __shared__ unsigned long long clist[CAP];
  __shared__ int ccnt;

  const int tid = threadIdx.x;
  const int lane = tid & 63, wave = tid >> 6;
  const int col = lane & 15, quad = lane >> 4;
  const int nw = blockIdx.x * 256 + wave * 64;
  const int vbase = blockIdx.y * vchunk;

  if (tid == 0) ccnt = 0;

  bf16x8 af[4];
#pragma unroll
  for (int f = 0; f < 4; ++f)
    af[f] = *(const bf16x8*)(zrowb + (size_t)(nw + f * 16 + col) * 32 + quad * 8);

  float thr[4][4];
#pragma unroll
  for (int f = 0; f < 4; ++f)
#pragma unroll
    for (int r = 0; r < 4; ++r)
      thr[f][r] = decf(smin[nw + f * 16 + quad * 4 + r]) + MARGIN_;
  // per-lane coarse bound: max of this lane's 16 per-point thresholds
  float tmax = fmaxf(
      fmaxf(fmaxf(fmaxf(thr[0][0], thr[0][1]), fmaxf(thr[0][2], thr[0][3])),
            fmaxf(fmaxf(thr[1][0], thr[1][1]), fmaxf(thr[1][2], thr[1][3]))),
      fmaxf(fmaxf(fmaxf(thr[2][0], thr[2][1]), fmaxf(thr[2][2], thr[2][3])),
            fmaxf(fmaxf(thr[3][0], thr[3][1]), fmaxf(thr[3][2], thr[3][3]))));

  for (int w0 = 0; w0 < vchunk; w0 += WIN) {
    __syncthreads();
    {
      int row = tid >> 1, half = tid & 1;       // full-row staging (see A)
      const bf16x8* src = (const bf16x8*)(ebf + (size_t)(vbase + w0 + row) * 32);
      bf16x8* dst = (bf16x8*)(elds + row * 40);
      dst[half * 2]     = src[half * 2];
      dst[half * 2 + 1] = src[half * 2 + 1];
      if (tid < WIN) selds[tid] = 0.5f * se[vbase + w0 + tid];
    }
    __syncthreads();
#pragma unroll 2
    for (int vv = 0; vv < WIN; vv += 32) {       // 2 slabs x 4 frags = 8 MFMA
      bf16x8 bfA = *(const bf16x8*)(elds + (vv + col) * 40 + quad * 8);
      bf16x8 bfB = *(const bf16x8*)(elds + (vv + 16 + col) * 40 + quad * 8);
      float sa = selds[vv + col], sb = selds[vv + 16 + col];
      f32x4 cinA = {sa, sa, sa, sa};
      f32x4 cinB = {sb, sb, sb, sb};
      f32x4 da[4], db[4];
#pragma unroll
      for (int f = 0; f < 4; ++f)
        da[f] = __builtin_amdgcn_mfma_f32_16x16x32_bf16(af[f], bfA, cinA, 0, 0, 0);
#pragma unroll
      for (int f = 0; f < 4; ++f)
        db[f] = __builtin_amdgcn_mfma_f32_16x16x32_bf16(af[f], bfB, cinB, 0, 0, 0);
      // coarse gate over all 32 values (no false negatives: d<=thr => g<=tmax)
      float m0  = min3f(da[0][0], da[0][1], da[0][2]);
      float m1  = min3f(da[0][3], da[1][0], da[1][1]);
      float m2  = min3f(da[1][2], da[1][3], da[2][0]);
      float m3  = min3f(da[2][1], da[2][2], da[2][3]);
      float m4  = min3f(da[3][0], da[3][1], da[3][2]);
      float m5  = min3f(da[3][3], db[0][0], db[0][1]);
      float m6  = min3f(db[0][2], db[0][3], db[1][0]);
      float m7  = min3f(db[1][1], db[1][2], db[1][3]);
      float m8  = min3f(db[2][0], db[2][1], db[2][2]);
      float m9  = min3f(db[2][3], db[3][0], db[3][1]);
      float m10 = min3f(db[3][2], db[3][3], m0);
      float m11 = min3f(m1, m2, m3);
      float m12 = min3f(m4, m5, m6);
      float m13 = min3f(m7, m8, m9);
      float g   = fminf(min3f(m10, m11, m12), m13);
      if (g <= tmax) {   // drill down per element
#pragma unroll
        for (int s = 0; s < 2; ++s) {
#pragma unroll
          for (int f = 0; f < 4; ++f) {
#pragma unroll
            for (int r = 0; r < 4; ++r) {
              float dv = (s == 0) ? da[f][r] : db[f][r];
              if (dv <= thr[f][r]) {
                int n = nw + f * 16 + quad * 4 + r;
                int v = vbase + w0 + vv + s * 16 + col;
                int slot = atomicAdd(&ccnt, 1);   // LDS atomic: fast
                if (slot < CAP) {
                  clist[slot] =
                      ((unsigned long long)(unsigned)n << 32) | (unsigned)v;
                } else {
                  // overflow fallback: exact inline (ascending-c fp order)
                  const float* zp = zrow + (size_t)n * 32;
                  const float* ep = embed + (size_t)v * 32;
                  float dot = 0.f, sz = 0.f;
#pragma unroll 1
                  for (int i = 0; i < 32; ++i) {
                    float zc = zp[i];
                    dot = fmaf(zc, ep[i], dot);
                    sz  = fmaf(zc, zc, sz);
                  }
                  float d = fmaf(-2.0f, dot, sz) + se[v];
                  unsigned long long key =
                      ((unsigned long long)encf(d) << 32) | (unsigned)v;
                  atomicMin(&keys[n], key);
                }
              }
            }
          }
        }
      }
    }
  }

  // batch exact-fp32 rescue (dot and sz both accumulate ascending c --
  // identical fp order to the passing formula)
  __syncthreads();
  int tot = min(ccnt, CAP);
  for (int j = tid; j < tot; j += 256) {
    unsigned long long cv = clist[j];
    int n = min((int)(cv >> 32), nmax - 1);
    int v = min((int)(cv & 0xffffffffull), V_ - 1);
    const float* zp = zrow + (size_t)n * 32;
    const float* ep = embed + (size_t)v * 32;
    float dot = 0.f, sz = 0.f;
#pragma unroll
    for (int i = 0; i < 32; ++i) {
      float zc = zp[i];
      dot = fmaf(zc, ep[i], dot);
      sz  = fmaf(zc, zc, sz);
    }
    float d = fmaf(-2.0f, dot, sz) + se[v];
    unsigned long long key =
        ((unsigned long long)encf(d) << 32) | (unsigned)v;
    atomicMin(&keys[n], key);
  }
}

// ---- upsample + f_rest update + loss + idx out + next-scale prep ----
// block = one (b,c) plane; blockIdx.x = b*32+c; tid = o*16+p
__global__ __launch_bounds__(256) void up_update_kernel(
    const float* __restrict__ embed, const unsigned long long* __restrict__ keys,
    const float* __restrict__ tbl, float* __restrict__ f_rest, int pn,
    float* __restrict__ zrow, short* __restrict__ zrowb,
    unsigned long long* __restrict__ keys_nb, unsigned int* __restrict__ smin_nb,
    int pn_next, int n_next,
    float* __restrict__ idx_out, float* __restrict__ loss_slot)
{
  __shared__ float sm[256];
  __shared__ float sm_e[64];
  const int tid = threadIdx.x;
  const int t = blockIdx.x * 256 + tid;
  const int p = tid & 15, o = tid >> 4;
  const int c = blockIdx.x & 31, b = blockIdx.x >> 5;
  const int pn2 = pn * pn;

  float pre = f_rest[t];
  sm[tid] = pre;
  if (tid < pn2) {
    int idx = keyidx(keys[b * pn2 + tid]);
    if (c == 0) idx_out[b * pn2 + tid] = (float)idx;
    sm_e[tid] = embed[(size_t)idx * 32 + c];
  }
  __syncthreads();

  // loss partial: recompute zavg from pre-update plane (== zrow exactly)
  float lsum = 0.f;
  if (tid < pn2) {
    int k = 16 / pn;
    int ph = tid / pn, pw = tid - ph * pn;
    float s = 0.f;
    for (int i = 0; i < k; ++i)
      for (int j = 0; j < k; ++j)
        s += sm[(ph * k + i) * 16 + (pw * k + j)];
    float zavg = s * (1.0f / (k * k));
    float d = sm_e[tid] - zavg;
    lsum = d * d;
  }
#pragma unroll
  for (int off = 32; off > 0; off >>= 1) lsum += __shfl_down(lsum, off, 64);
  if ((tid & 63) == 0)
    atomicAdd(loss_slot + ((blockIdx.x & 127) << 4), lsum);

  // bicubic upsample (ref: h-einsum first, then w)
  const float* Wo = tbl + o * 8;
  const float* Wp = tbl + p * 8;
  float acc = 0.f;
  for (int w = 0; w < pn; ++w) {
    float inner = 0.f;
    for (int h = 0; h < pn; ++h)
      inner = fmaf(Wo[h], sm_e[h * pn + w], inner);
    acc = fmaf(Wp[w], inner, acc);
  }
  float nr = pre - acc;
  f_rest[t] = nr;

  __syncthreads();
  sm[tid] = nr;
  __syncthreads();
  const int pnn2 = pn_next * pn_next;
  if (tid < pnn2) {
    int ph = tid / pn_next, pw = tid - ph * pn_next;
    int k = 16 / pn_next;
    float s = 0.f;
    for (int i = 0; i < k; ++i)
      for (int j = 0; j < k; ++j)
        s += sm[(ph * k + i) * 16 + (pw * k + j)];
    float zavg = s * (1.0f / (k * k));
    size_t nn = (size_t)(b * pnn2 + tid);
    zrow[nn * 32 + c]  = zavg;          // exact f32 for rescue/loss
    zrowb[nn * 32 + c] = f2bf(-zavg);   // negated bf16 A-frag source
  }
  if (t < n_next) {                // reset ping-pong buffers for next scale
    keys_nb[t] = ~0ull;
    smin_nb[t] = 0xFFFFFFFFu;
  }
}

// -- final scale (pn=16): out = (z - f_rest) + embed[idx], idx out, loss --
__global__ __launch_bounds__(256) void final_add_kernel(
    const float* __restrict__ z, const float* __restrict__ f_rest,
    const float* __restrict__ embed, const unsigned long long* __restrict__ keys,
    float* __restrict__ f_hat, float* __restrict__ idx_out,
    float* __restrict__ loss_slot)
{
  const int tid = threadIdx.x;
  const int t = blockIdx.x * 256 + tid;
  const int c = blockIdx.x & 31, b = blockIdx.x >> 5;
  const int n = b * 256 + tid;
  int idx = keyidx(keys[n]);
  if (c == 0) idx_out[n] = (float)idx;
  float e = embed[(size_t)idx * 32 + c];
  float fr = f_rest[t];
  f_hat[t] = (z[t] - fr) + e;   // f_hat = sum of zq (err ~1e-6)
  float d = e - fr;             // fr == zavg at pn=16 bit-exactly
  float lsum = d * d;
#pragma unroll
  for (int off = 32; off > 0; off >>= 1) lsum += __shfl_down(lsum, off, 64);
  if ((tid & 63) == 0)
    atomicAdd(loss_slot + ((blockIdx.x & 127) << 4), lsum);
}

// ------------- final loss reduce: 5 scales x 128 padded slots -------------
__global__ __launch_bounds__(128) void loss_final_kernel(
    const float* __restrict__ loss_slots, float* __restrict__ out_loss)
{
  __shared__ float lred[2];
  const int tid = threadIdx.x;   // 128 threads = 2 waves
  const float numel[5] = {8192.f, 32768.f, 131072.f, 524288.f, 2097152.f};
  float tot = 0.f;
  for (int s = 0; s < 5; ++s) {
    float x = loss_slots[s * 2048 + tid * 16];
#pragma unroll
    for (int off = 32; off > 0; off >>= 1) x += __shfl_down(x, off, 64);
    if ((tid & 63) == 0) lred[tid >> 6] = x;
    __syncthreads();
    if (tid == 0) {
      float m = (lred[0] + lred[1]) / numel[s];
      tot += 0.25f * m + m;        // beta*mean + mean
    }
    __syncthreads();
  }
  if (tid == 0) out_loss[0] = tot / 5.f;
}

// =========================== host launcher ===========================
extern "C" void kernel_launch(void* const* d_in, const int* in_sizes, int n_in,
                              void* d_out, int out_size, void* d_ws, size_t ws_size,
                              hipStream_t stream)
{
  const float* z     = (const float*)d_in[0];
  const float* embed = (const float*)d_in[1];
  float* out = (float*)d_out;
  float* ws  = (float*)d_ws;

  // ws layout (float slots), total 5569024 floats ~= 21.2 MiB
  float* f_rest  = ws;                                   // 2097152
  float* zrow    = ws + 2097152;                         // [65536][32] f32
  short* zrowb   = (short*)(ws + 4194304);               // [65536][32] bf16(-z)
  short* ebf     = (short*)(ws + 5242880);               // 131072 shorts
  float* se      = ws + 5308416;                         // 4096
  unsigned int* smin0 = (unsigned int*)(ws + 5312512);   // 65536 u32
  unsigned int* smin1 = (unsigned int*)(ws + 5378048);   // 16384 u32
  unsigned long long* keys0 = (unsigned long long*)(ws + 5394432); // 65536 u64
  unsigned long long* keys1 = (unsigned long long*)(ws + 5525504); // 16384 u64
  float* loss_slots = ws + 5558272;                      // 5*128*16 = 10240
  float* tables     = ws + 5568512;                      // 512

  unsigned long long* keysb[2] = {keys0, keys1};
  unsigned int*       sminb[2] = {smin0, smin1};

  setup_kernel<<<NTOT / 256, 256, 0, stream>>>(z, embed, f_rest, zrow, zrowb,
                                               ebf, se, tables, loss_slots,
                                               keys0, smin0);

  const int PN[5]  = {1, 2, 4, 8, 16};
  // v-chunks; vchunk = V_/NVC must be a multiple of WIN=128
  const int NVC[5] = {32, 32, 32, 16, 16};
  int idx_off = NTOT;
  for (int i = 0; i < 5; ++i) {
    int pn = PN[i];
    int N  = B_ * pn * pn;
    int vchunk = V_ / NVC[i];
    unsigned long long* kb = keysb[i & 1];
    unsigned int*       sb = sminb[i & 1];
    dim3 g(N / 256, NVC[i]);                  // 4-frag waves: 256 points/block
    vq_phaseA_kernel<<<g, 256, 0, stream>>>(zrowb, ebf, se, sb, vchunk);
    vq_phaseB_kernel<<<g, 256, 0, stream>>>(zrowb, ebf, se, sb, zrow, embed,
                                            kb, vchunk, N);
    if (i < 4) {
      int pnn = PN[i + 1];
      up_update_kernel<<<NTOT / 256, 256, 0, stream>>>(
          embed, kb, tables + i * 128, f_rest, pn,
          zrow, zrowb, keysb[(i + 1) & 1], sminb[(i + 1) & 1],
          pnn, B_ * pnn * pnn, out + idx_off, loss_slots + i * 2048);
    } else {
      final_add_kernel<<<NTOT / 256, 256, 0, stream>>>(
          z, f_rest, embed, kb, out, out + idx_off, loss_slots + 4 * 2048);
    }
    idx_off += N;
  }
  loss_final_kernel<<<1, 128, 0, stream>>>(loss_slots, out + 2184448);
}